// Round 3
// baseline (734.269 us; speedup 1.0000x reference)
//
#include <hip/hip_runtime.h>

#define NN 50000
#define EE 800000
#define DD 96

// NOTE: harness passes ALL integer inputs as int32 — edge_index is const int*
// (reading it as int64 was rounds 1-2's OOB crash).

// ---------------- degree / dinv precompute (shared by both layers) ----------
// dinv buffer doubles as the float degree accumulator: init 1.0 (self-loop),
// atomicAdd 1.0 per incident dst edge (exact: deg << 2^24), then rsqrt in place.

__global__ void k_deg_init(float* __restrict__ dinv) {
    int i = blockIdx.x * blockDim.x + threadIdx.x;
    if (i < NN) dinv[i] = 1.0f;
}

__global__ void k_deg_acc(const int* __restrict__ ei, float* __restrict__ dinv) {
    int e = blockIdx.x * blockDim.x + threadIdx.x;
    if (e < EE) atomicAdd(&dinv[ei[EE + e]], 1.0f);
}

__global__ void k_rsqrt(float* __restrict__ dinv) {
    int i = blockIdx.x * blockDim.x + threadIdx.x;
    if (i < NN) dinv[i] = rsqrtf(dinv[i]);
}

// ---------------- GEMM: out[N,96] = (relu?)in[N,96] @ W[96,96] --------------
// 384 threads = 16 row-threads x 24 col4-groups; 32 rows per block.
// W (36 KB) + row tile (12 KB) in LDS; per-thread 2x4 register tile.

__global__ __launch_bounds__(384) void k_gemm(const float* __restrict__ in,
                                              const float* __restrict__ W,
                                              float* __restrict__ out,
                                              int relu_in) {
    __shared__ float Wl[DD * DD];
    __shared__ float Rl[32][DD];
    int t = threadIdx.x;
    for (int i = t; i < DD * DD; i += 384) Wl[i] = W[i];
    int row0 = blockIdx.x * 32;
    for (int i = t; i < 32 * DD; i += 384) {
        int rr = i / DD, cc = i - rr * DD;
        int r = row0 + rr;
        float v = (r < NN) ? in[r * DD + cc] : 0.f;
        if (relu_in) v = fmaxf(v, 0.f);
        Rl[rr][cc] = v;
    }
    __syncthreads();

    int tx = t % 24;        // col group
    int ry = t / 24;        // 0..15 -> rows ry, ry+16
    int c0 = tx * 4;
    float a0x = 0.f, a0y = 0.f, a0z = 0.f, a0w = 0.f;
    float a1x = 0.f, a1y = 0.f, a1z = 0.f, a1w = 0.f;
#pragma unroll 8
    for (int k = 0; k < DD; ++k) {
        float4 w = *(const float4*)&Wl[k * DD + c0];
        float r0 = Rl[ry][k];
        float r1 = Rl[ry + 16][k];
        a0x += r0 * w.x; a0y += r0 * w.y; a0z += r0 * w.z; a0w += r0 * w.w;
        a1x += r1 * w.x; a1y += r1 * w.y; a1z += r1 * w.z; a1w += r1 * w.w;
    }
    int r0i = row0 + ry, r1i = row0 + ry + 16;
    if (r0i < NN) *(float4*)&out[r0i * DD + c0] = make_float4(a0x, a0y, a0z, a0w);
    if (r1i < NN) *(float4*)&out[r1i * DD + c0] = make_float4(a1x, a1y, a1z, a1w);
}

// ---------------- self-loop + bias init: out = dinv^2 * h + b (float4) ------

__global__ void k_init_out(const float* __restrict__ h,
                           const float* __restrict__ dinv,
                           const float* __restrict__ b,
                           float* __restrict__ out) {
    int i = blockIdx.x * blockDim.x + threadIdx.x;   // float4 index
    if (i < NN * DD / 4) {
        int v  = i / (DD / 4);
        int x4 = i - v * (DD / 4);
        float di = dinv[v];
        float s  = di * di;
        float4 hv = ((const float4*)h)[i];
        float4 bv = ((const float4*)b)[x4];
        ((float4*)out)[i] = make_float4(s * hv.x + bv.x, s * hv.y + bv.y,
                                        s * hv.z + bv.z, s * hv.w + bv.w);
    }
}

// ---------------- edge scatter: out[d] += dinv[s]*dinv[d] * h[s] ------------
// 384 threads = 4 edges x 96 features per block; endpoint + dinv gathers are
// L1/L2-resident.

__global__ __launch_bounds__(384) void k_scatter(const float* __restrict__ h,
                                                 const int* __restrict__ ei,
                                                 const float* __restrict__ dinv,
                                                 float* __restrict__ out) {
    int x = threadIdx.x % DD;
    int ey = threadIdx.x / DD;
    int e = blockIdx.x * 4 + ey;
    if (e < EE) {
        int s = ei[e];
        int d = ei[EE + e];
        float nv = dinv[s] * dinv[d];
        atomicAdd(&out[d * DD + x], nv * h[s * DD + x]);
    }
}

// ---------------- final: out = relu(in) (float4) ----------------------------

__global__ void k_relu_copy(const float* __restrict__ in, float* __restrict__ out) {
    int i = blockIdx.x * blockDim.x + threadIdx.x;
    if (i < NN * DD / 4) {
        float4 v = ((const float4*)in)[i];
        ((float4*)out)[i] = make_float4(fmaxf(v.x, 0.f), fmaxf(v.y, 0.f),
                                        fmaxf(v.z, 0.f), fmaxf(v.w, 0.f));
    }
}

// ----------------------------------------------------------------------------

extern "C" void kernel_launch(void* const* d_in, const int* in_sizes, int n_in,
                              void* d_out, int out_size, void* d_ws, size_t ws_size,
                              hipStream_t stream) {
    const float* x  = (const float*)d_in[0];
    const int*   ei = (const int*)d_in[1];   // harness passes integers as int32
    const float* W1 = (const float*)d_in[2];
    const float* b1 = (const float*)d_in[3];
    const float* W2 = (const float*)d_in[4];
    const float* b2 = (const float*)d_in[5];
    float* out = (float*)d_out;

    // Minimal workspace: dinv (200 KB, 256B-aligned) + one N*D float buffer.
    char* p = (char*)d_ws;
    float* dinv = (float*)p;
    p += ((size_t)NN * sizeof(float) + 255) & ~(size_t)255;
    float* tmp = (float*)p;                     // N*D floats (19.2 MB)
    // total ws used: ~19.4 MB. d_out doubles as scratch for per-layer h.

    const int ND4 = NN * DD / 4;

    k_deg_init<<<(NN + 255) / 256, 256, 0, stream>>>(dinv);
    k_deg_acc<<<(EE + 255) / 256, 256, 0, stream>>>(ei, dinv);
    k_rsqrt<<<(NN + 255) / 256, 256, 0, stream>>>(dinv);

    // ---- layer 1: h1 = x@W1 (-> d_out) ; tmp = dinv^2*h1 + b1 ; tmp += edges
    k_gemm<<<(NN + 31) / 32, 384, 0, stream>>>(x, W1, out, 0);
    k_init_out<<<(ND4 + 255) / 256, 256, 0, stream>>>(out, dinv, b1, tmp);
    k_scatter<<<(EE + 3) / 4, 384, 0, stream>>>(out, ei, dinv, tmp);

    // ---- layer 2: h2 = relu(tmp)@W2 (-> d_out) ; tmp = dinv^2*h2 + b2 ;
    //              tmp += edges ; out = relu(tmp)
    k_gemm<<<(NN + 31) / 32, 384, 0, stream>>>(tmp, W2, out, 1);
    k_init_out<<<(ND4 + 255) / 256, 256, 0, stream>>>(out, dinv, b2, tmp);
    k_scatter<<<(EE + 3) / 4, 384, 0, stream>>>(out, ei, dinv, tmp);
    k_relu_copy<<<(ND4 + 255) / 256, 256, 0, stream>>>(tmp, out);
}

// Round 4
// 432.023 us; speedup vs baseline: 1.6996x; 1.6996x over previous
//
#include <hip/hip_runtime.h>

#define NN 50000
#define EE 800000
#define DD 96

// Harness passes integer inputs as int32 — edge_index is const int* (2,E).

// ---------------- CSR build (by dst), shared by both layers -----------------

__global__ void k_zero2(int* __restrict__ a, int* __restrict__ b) {
    int i = blockIdx.x * blockDim.x + threadIdx.x;
    if (i < NN) { a[i] = 0; b[i] = 0; }
}

__global__ void k_count(const int* __restrict__ ei, int* __restrict__ cnt) {
    int e = blockIdx.x * blockDim.x + threadIdx.x;
    if (e < EE) atomicAdd(&cnt[ei[EE + e]], 1);
}

// Single-block exclusive scan of cnt -> rp, plus dinv = rsqrt(cnt+1).
#define CHUNK 49  // 1024*49 >= NN
__global__ __launch_bounds__(1024) void k_scan(const int* __restrict__ cnt,
                                               int* __restrict__ rp,
                                               float* __restrict__ dinv) {
    __shared__ int part[1024];
    int t = threadIdx.x;
    int lo = t * CHUNK, hi = min(lo + CHUNK, NN);
    int s = 0;
    for (int i = lo; i < hi; ++i) s += cnt[i];
    part[t] = s;
    __syncthreads();
    for (int off = 1; off < 1024; off <<= 1) {   // Hillis-Steele inclusive
        int v = (t >= off) ? part[t - off] : 0;
        __syncthreads();
        part[t] += v;
        __syncthreads();
    }
    int run = part[t] - s;                        // exclusive chunk offset
    for (int i = lo; i < hi; ++i) {
        rp[i] = run;
        run += cnt[i];
        dinv[i] = rsqrtf((float)(cnt[i] + 1));    // +1 self-loop
    }
    if (t == 1023) rp[NN] = part[1023];
}

__global__ void k_fill(const int* __restrict__ ei, const int* __restrict__ rp,
                       int* __restrict__ cursor, int* __restrict__ col) {
    int e = blockIdx.x * blockDim.x + threadIdx.x;
    if (e < EE) {
        int d = ei[EE + e];
        int p = rp[d] + atomicAdd(&cursor[d], 1);
        col[p] = ei[e];
    }
}

// ---------------- GEMM: out[N,96] = in[N,96] @ W[96,96] ---------------------
// 384 threads = 16 row-threads x 24 col4-groups; 32 rows per block.

__global__ __launch_bounds__(384) void k_gemm(const float* __restrict__ in,
                                              const float* __restrict__ W,
                                              float* __restrict__ out) {
    __shared__ float Wl[DD * DD];
    __shared__ float Rl[32][DD];
    int t = threadIdx.x;
    for (int i = t; i < DD * DD; i += 384) Wl[i] = W[i];
    int row0 = blockIdx.x * 32;
    for (int i = t; i < 32 * DD; i += 384) {
        int rr = i / DD, cc = i - rr * DD;
        int r = row0 + rr;
        Rl[rr][cc] = (r < NN) ? in[r * DD + cc] : 0.f;
    }
    __syncthreads();

    int tx = t % 24;        // col group
    int ry = t / 24;        // rows ry, ry+16
    int c0 = tx * 4;
    float a0x = 0.f, a0y = 0.f, a0z = 0.f, a0w = 0.f;
    float a1x = 0.f, a1y = 0.f, a1z = 0.f, a1w = 0.f;
#pragma unroll 8
    for (int k = 0; k < DD; ++k) {
        float4 w = *(const float4*)&Wl[k * DD + c0];
        float r0 = Rl[ry][k];
        float r1 = Rl[ry + 16][k];
        a0x += r0 * w.x; a0y += r0 * w.y; a0z += r0 * w.z; a0w += r0 * w.w;
        a1x += r1 * w.x; a1y += r1 * w.y; a1z += r1 * w.z; a1w += r1 * w.w;
    }
    int r0i = row0 + ry, r1i = row0 + ry + 16;
    if (r0i < NN) *(float4*)&out[r0i * DD + c0] = make_float4(a0x, a0y, a0z, a0w);
    if (r1i < NN) *(float4*)&out[r1i * DD + c0] = make_float4(a1x, a1y, a1z, a1w);
}

// ---------------- pull aggregation (fused norm + self-loop + bias + relu) ---
// out[d,x] = relu( dinv[d]*sum_{s in in(d)} dinv[s]*h[s,x]
//                  + dinv[d]^2*h[d,x] + b[x] )
// 384 threads = 4 nodes x 96 features. Zero atomics; register accumulation.

__global__ __launch_bounds__(384) void k_pull(const float* __restrict__ h,
                                              const int* __restrict__ rp,
                                              const int* __restrict__ col,
                                              const float* __restrict__ dinv,
                                              const float* __restrict__ b,
                                              float* __restrict__ out) {
    int x = threadIdx.x % DD;
    int ny = threadIdx.x / DD;
    int d = blockIdx.x * 4 + ny;
    if (d >= NN) return;
    int j0 = rp[d], j1 = rp[d + 1];
    float acc0 = 0.f, acc1 = 0.f;
    int j = j0;
    for (; j + 1 < j1; j += 2) {
        int s0 = col[j], s1 = col[j + 1];
        acc0 += dinv[s0] * h[s0 * DD + x];
        acc1 += dinv[s1] * h[s1 * DD + x];
    }
    if (j < j1) { int s0 = col[j]; acc0 += dinv[s0] * h[s0 * DD + x]; }
    float dd = dinv[d];
    float v = dd * (acc0 + acc1) + dd * dd * h[d * DD + x] + b[x];
    out[d * DD + x] = fmaxf(v, 0.f);   // ReLU follows both conv layers
}

// ----------------------------------------------------------------------------

extern "C" void kernel_launch(void* const* d_in, const int* in_sizes, int n_in,
                              void* d_out, int out_size, void* d_ws, size_t ws_size,
                              hipStream_t stream) {
    const float* x  = (const float*)d_in[0];
    const int*   ei = (const int*)d_in[1];
    const float* W1 = (const float*)d_in[2];
    const float* b1 = (const float*)d_in[3];
    const float* W2 = (const float*)d_in[4];
    const float* b2 = (const float*)d_in[5];
    float* out = (float*)d_out;

    // Workspace: cnt, cursor, rp, col, dinv, tmp  (~23.2 MB)
    char* p = (char*)d_ws;
    int*   cnt    = (int*)p;   p += ((size_t)NN * 4 + 255) & ~(size_t)255;
    int*   cursor = (int*)p;   p += ((size_t)NN * 4 + 255) & ~(size_t)255;
    int*   rp     = (int*)p;   p += ((size_t)(NN + 1) * 4 + 255) & ~(size_t)255;
    int*   col    = (int*)p;   p += ((size_t)EE * 4 + 255) & ~(size_t)255;
    float* dinv   = (float*)p; p += ((size_t)NN * 4 + 255) & ~(size_t)255;
    float* tmp    = (float*)p;                    // N*D floats (19.2 MB)

    // ---- CSR build (once) ----
    k_zero2<<<(NN + 255) / 256, 256, 0, stream>>>(cnt, cursor);
    k_count<<<(EE + 255) / 256, 256, 0, stream>>>(ei, cnt);
    k_scan<<<1, 1024, 0, stream>>>(cnt, rp, dinv);
    k_fill<<<(EE + 255) / 256, 256, 0, stream>>>(ei, rp, cursor, col);

    // ---- layer 1: tmp = x@W1 ; d_out = relu(agg(tmp)) ----
    k_gemm<<<(NN + 31) / 32, 384, 0, stream>>>(x, W1, tmp);
    k_pull<<<(NN + 3) / 4, 384, 0, stream>>>(tmp, rp, col, dinv, b1, out);

    // ---- layer 2: tmp = d_out@W2 ; d_out = relu(agg(tmp)) ----
    k_gemm<<<(NN + 31) / 32, 384, 0, stream>>>(out, W2, tmp);
    k_pull<<<(NN + 3) / 4, 384, 0, stream>>>(tmp, rp, col, dinv, b2, out);
}

// Round 5
// 282.404 us; speedup vs baseline: 2.6001x; 1.5298x over previous
//
#include <hip/hip_runtime.h>

#define NN 50000
#define EE 800000
#define DD 96
#define NB 196          // ceil(NN/256) scan blocks

// Harness passes integer inputs as int32 — edge_index is const int* (2,E).

// ---------------- CSR build (by dst), shared by both layers -----------------

__global__ void k_zero(int* __restrict__ cnt) {
    int i = blockIdx.x * blockDim.x + threadIdx.x;
    if (i < NN) cnt[i] = 0;
}

__global__ void k_count(const int* __restrict__ ei, int* __restrict__ cnt) {
    int e = blockIdx.x * blockDim.x + threadIdx.x;
    if (e < EE) atomicAdd(&cnt[ei[EE + e]], 1);
}

// Level 1: per-block exclusive scan of 256 counts; block total -> bsum.
__global__ __launch_bounds__(256) void k_bscan(const int* __restrict__ cnt,
                                               int* __restrict__ part,
                                               int* __restrict__ bsum) {
    __shared__ int sh[256];
    int t = threadIdx.x;
    int g = blockIdx.x * 256 + t;
    int v = (g < NN) ? cnt[g] : 0;
    sh[t] = v;
    __syncthreads();
    for (int off = 1; off < 256; off <<= 1) {
        int u = (t >= off) ? sh[t - off] : 0;
        __syncthreads();
        sh[t] += u;
        __syncthreads();
    }
    if (g < NN) part[g] = sh[t] - v;          // exclusive within block
    if (t == 255) bsum[blockIdx.x] = sh[255]; // block total
}

// Level 2: exclusive scan of the NB block sums (single tiny block).
__global__ __launch_bounds__(256) void k_scan2(int* __restrict__ bsum) {
    __shared__ int sh[256];
    int t = threadIdx.x;
    int v = (t < NB) ? bsum[t] : 0;
    sh[t] = v;
    __syncthreads();
    for (int off = 1; off < 256; off <<= 1) {
        int u = (t >= off) ? sh[t - off] : 0;
        __syncthreads();
        sh[t] += u;
        __syncthreads();
    }
    if (t < NB) bsum[t] = sh[t] - v;          // exclusive block offsets
}

// Level 3: rp = part + bsum[blk]; dinv = rsqrt(deg+1); re-zero part (cursor).
__global__ void k_final(const int* __restrict__ cnt, int* __restrict__ part,
                        const int* __restrict__ bsum, int* __restrict__ rp,
                        float* __restrict__ dinv) {
    int i = blockIdx.x * blockDim.x + threadIdx.x;
    if (i < NN) {
        rp[i] = part[i] + bsum[i >> 8];
        dinv[i] = rsqrtf((float)(cnt[i] + 1));   // +1 self-loop
        part[i] = 0;                              // becomes fill cursor
    }
    if (i == 0) rp[NN] = EE;
}

__global__ void k_fill(const int* __restrict__ ei, const int* __restrict__ rp,
                       int* __restrict__ cursor, int* __restrict__ col) {
    int e = blockIdx.x * blockDim.x + threadIdx.x;
    if (e < EE) {
        int d = ei[EE + e];
        int p = rp[d] + atomicAdd(&cursor[d], 1);
        col[p] = ei[e];
    }
}

// ---------------- GEMM: out[N,96] = in[N,96] @ W[96,96] ---------------------
// 384 threads = 16 row-threads x 24 col4-groups; 32 rows per block.

__global__ __launch_bounds__(384) void k_gemm(const float* __restrict__ in,
                                              const float* __restrict__ W,
                                              float* __restrict__ out) {
    __shared__ float Wl[DD * DD];
    __shared__ float Rl[32][DD];
    int t = threadIdx.x;
    for (int i = t; i < DD * DD; i += 384) Wl[i] = W[i];
    int row0 = blockIdx.x * 32;
    for (int i = t; i < 32 * DD; i += 384) {
        int rr = i / DD, cc = i - rr * DD;
        int r = row0 + rr;
        Rl[rr][cc] = (r < NN) ? in[r * DD + cc] : 0.f;
    }
    __syncthreads();

    int tx = t % 24;        // col group
    int ry = t / 24;        // rows ry, ry+16
    int c0 = tx * 4;
    float a0x = 0.f, a0y = 0.f, a0z = 0.f, a0w = 0.f;
    float a1x = 0.f, a1y = 0.f, a1z = 0.f, a1w = 0.f;
#pragma unroll 8
    for (int k = 0; k < DD; ++k) {
        float4 w = *(const float4*)&Wl[k * DD + c0];
        float r0 = Rl[ry][k];
        float r1 = Rl[ry + 16][k];
        a0x += r0 * w.x; a0y += r0 * w.y; a0z += r0 * w.z; a0w += r0 * w.w;
        a1x += r1 * w.x; a1y += r1 * w.y; a1z += r1 * w.z; a1w += r1 * w.w;
    }
    int r0i = row0 + ry, r1i = row0 + ry + 16;
    if (r0i < NN) *(float4*)&out[r0i * DD + c0] = make_float4(a0x, a0y, a0z, a0w);
    if (r1i < NN) *(float4*)&out[r1i * DD + c0] = make_float4(a1x, a1y, a1z, a1w);
}

// ---------------- pull aggregation (fused norm + self-loop + bias + relu) ---
// out[d,x] = relu( dinv[d]*sum_{s in in(d)} dinv[s]*h[s,x]
//                  + dinv[d]^2*h[d,x] + b[x] )
// 384 threads = 4 nodes x 96 features. Zero atomics; 4-way MLP unroll.

__global__ __launch_bounds__(384) void k_pull(const float* __restrict__ h,
                                              const int* __restrict__ rp,
                                              const int* __restrict__ col,
                                              const float* __restrict__ dinv,
                                              const float* __restrict__ b,
                                              float* __restrict__ out) {
    int x = threadIdx.x % DD;
    int ny = threadIdx.x / DD;
    int d = blockIdx.x * 4 + ny;
    if (d >= NN) return;
    int j0 = rp[d], j1 = rp[d + 1];
    float acc0 = 0.f, acc1 = 0.f, acc2 = 0.f, acc3 = 0.f;
    int j = j0;
    for (; j + 3 < j1; j += 4) {
        int s0 = col[j], s1 = col[j + 1], s2 = col[j + 2], s3 = col[j + 3];
        acc0 += dinv[s0] * h[s0 * DD + x];
        acc1 += dinv[s1] * h[s1 * DD + x];
        acc2 += dinv[s2] * h[s2 * DD + x];
        acc3 += dinv[s3] * h[s3 * DD + x];
    }
    for (; j < j1; ++j) { int s = col[j]; acc0 += dinv[s] * h[s * DD + x]; }
    float dd = dinv[d];
    float v = dd * ((acc0 + acc1) + (acc2 + acc3)) + dd * dd * h[d * DD + x] + b[x];
    out[d * DD + x] = fmaxf(v, 0.f);   // ReLU follows both conv layers
}

// ----------------------------------------------------------------------------

extern "C" void kernel_launch(void* const* d_in, const int* in_sizes, int n_in,
                              void* d_out, int out_size, void* d_ws, size_t ws_size,
                              hipStream_t stream) {
    const float* x  = (const float*)d_in[0];
    const int*   ei = (const int*)d_in[1];
    const float* W1 = (const float*)d_in[2];
    const float* b1 = (const float*)d_in[3];
    const float* W2 = (const float*)d_in[4];
    const float* b2 = (const float*)d_in[5];
    float* out = (float*)d_out;

    // Workspace: cnt, part/cursor, rp, col, dinv, bsum, tmp  (~23.2 MB)
    char* p = (char*)d_ws;
    int*   cnt    = (int*)p;   p += ((size_t)NN * 4 + 255) & ~(size_t)255;
    int*   part   = (int*)p;   p += ((size_t)NN * 4 + 255) & ~(size_t)255;  // doubles as fill cursor
    int*   rp     = (int*)p;   p += ((size_t)(NN + 1) * 4 + 255) & ~(size_t)255;
    int*   col    = (int*)p;   p += ((size_t)EE * 4 + 255) & ~(size_t)255;
    float* dinv   = (float*)p; p += ((size_t)NN * 4 + 255) & ~(size_t)255;
    int*   bsum   = (int*)p;   p += ((size_t)NB * 4 + 255) & ~(size_t)255;
    float* tmp    = (float*)p;                    // N*D floats (19.2 MB)

    // ---- CSR build ----
    k_zero<<<(NN + 255) / 256, 256, 0, stream>>>(cnt);
    k_count<<<(EE + 255) / 256, 256, 0, stream>>>(ei, cnt);
    k_bscan<<<NB, 256, 0, stream>>>(cnt, part, bsum);
    k_scan2<<<1, 256, 0, stream>>>(bsum);
    k_final<<<(NN + 255) / 256, 256, 0, stream>>>(cnt, part, bsum, rp, dinv);
    k_fill<<<(EE + 255) / 256, 256, 0, stream>>>(ei, rp, part, col);

    // ---- layer 1: tmp = x@W1 ; d_out = relu(agg(tmp)) ----
    k_gemm<<<(NN + 31) / 32, 384, 0, stream>>>(x, W1, tmp);
    k_pull<<<(NN + 3) / 4, 384, 0, stream>>>(tmp, rp, col, dinv, b1, out);

    // ---- layer 2: tmp = d_out@W2 ; d_out = relu(agg(tmp)) ----
    k_gemm<<<(NN + 31) / 32, 384, 0, stream>>>(out, W2, tmp);
    k_pull<<<(NN + 3) / 4, 384, 0, stream>>>(tmp, rp, col, dinv, b2, out);
}

// Round 6
// 245.494 us; speedup vs baseline: 2.9910x; 1.1503x over previous
//
#include <hip/hip_runtime.h>

#define NN 50000
#define EE 800000
#define DD 96
#define NB 196          // ceil(NN/256) scan blocks

// Harness passes integer inputs as int32 — edge_index is const int* (2,E).

// ---------------- CSR build (by dst), shared by both layers -----------------

__global__ void k_zero(int* __restrict__ cnt) {
    int i = blockIdx.x * blockDim.x + threadIdx.x;
    if (i < NN) cnt[i] = 0;
}

__global__ void k_count(const int* __restrict__ ei, int* __restrict__ cnt) {
    int e = blockIdx.x * blockDim.x + threadIdx.x;
    if (e < EE) atomicAdd(&cnt[ei[EE + e]], 1);
}

// Level 1: per-block exclusive scan of 256 counts; block total -> bsum.
__global__ __launch_bounds__(256) void k_bscan(const int* __restrict__ cnt,
                                               int* __restrict__ part,
                                               int* __restrict__ bsum) {
    __shared__ int sh[256];
    int t = threadIdx.x;
    int g = blockIdx.x * 256 + t;
    int v = (g < NN) ? cnt[g] : 0;
    sh[t] = v;
    __syncthreads();
    for (int off = 1; off < 256; off <<= 1) {
        int u = (t >= off) ? sh[t - off] : 0;
        __syncthreads();
        sh[t] += u;
        __syncthreads();
    }
    if (g < NN) part[g] = sh[t] - v;          // exclusive within block
    if (t == 255) bsum[blockIdx.x] = sh[255]; // block total
}

// Level 2: exclusive scan of the NB block sums (single tiny block).
__global__ __launch_bounds__(256) void k_scan2(int* __restrict__ bsum) {
    __shared__ int sh[256];
    int t = threadIdx.x;
    int v = (t < NB) ? bsum[t] : 0;
    sh[t] = v;
    __syncthreads();
    for (int off = 1; off < 256; off <<= 1) {
        int u = (t >= off) ? sh[t - off] : 0;
        __syncthreads();
        sh[t] += u;
        __syncthreads();
    }
    if (t < NB) bsum[t] = sh[t] - v;          // exclusive block offsets
}

// Level 3: rp = part + bsum[blk]; dinv = rsqrt(deg+1); re-zero part (cursor).
__global__ void k_final(const int* __restrict__ cnt, int* __restrict__ part,
                        const int* __restrict__ bsum, int* __restrict__ rp,
                        float* __restrict__ dinv) {
    int i = blockIdx.x * blockDim.x + threadIdx.x;
    if (i < NN) {
        rp[i] = part[i] + bsum[i >> 8];
        dinv[i] = rsqrtf((float)(cnt[i] + 1));   // +1 self-loop
        part[i] = 0;                              // becomes fill cursor
    }
    if (i == 0) rp[NN] = EE;
}

__global__ void k_fill(const int* __restrict__ ei, const int* __restrict__ rp,
                       int* __restrict__ cursor, int* __restrict__ col) {
    int e = blockIdx.x * blockDim.x + threadIdx.x;
    if (e < EE) {
        int d = ei[EE + e];
        int p = rp[d] + atomicAdd(&cursor[d], 1);
        col[p] = ei[e];
    }
}

// ---------------- GEMM: out[r] = dinv[r] * (in[r] @ W)  ---------------------
// 384 threads = 16 row-threads x 24 col4-groups; 32 rows per block.
// dinv pre-scaling folds the per-source norm into the GEMM epilogue so the
// pull kernel is a pure float4 sum.

__global__ __launch_bounds__(384) void k_gemm(const float* __restrict__ in,
                                              const float* __restrict__ W,
                                              const float* __restrict__ dinv,
                                              float* __restrict__ out) {
    __shared__ float Wl[DD * DD];
    __shared__ float Rl[32][DD];
    int t = threadIdx.x;
    for (int i = t; i < DD * DD; i += 384) Wl[i] = W[i];
    int row0 = blockIdx.x * 32;
    for (int i = t; i < 32 * DD; i += 384) {
        int rr = i / DD, cc = i - rr * DD;
        int r = row0 + rr;
        Rl[rr][cc] = (r < NN) ? in[r * DD + cc] : 0.f;
    }
    __syncthreads();

    int tx = t % 24;        // col group
    int ry = t / 24;        // rows ry, ry+16
    int c0 = tx * 4;
    float a0x = 0.f, a0y = 0.f, a0z = 0.f, a0w = 0.f;
    float a1x = 0.f, a1y = 0.f, a1z = 0.f, a1w = 0.f;
#pragma unroll 8
    for (int k = 0; k < DD; ++k) {
        float4 w = *(const float4*)&Wl[k * DD + c0];
        float r0 = Rl[ry][k];
        float r1 = Rl[ry + 16][k];
        a0x += r0 * w.x; a0y += r0 * w.y; a0z += r0 * w.z; a0w += r0 * w.w;
        a1x += r1 * w.x; a1y += r1 * w.y; a1z += r1 * w.z; a1w += r1 * w.w;
    }
    int r0i = row0 + ry, r1i = row0 + ry + 16;
    if (r0i < NN) {
        float s = dinv[r0i];
        *(float4*)&out[r0i * DD + c0] = make_float4(s*a0x, s*a0y, s*a0z, s*a0w);
    }
    if (r1i < NN) {
        float s = dinv[r1i];
        *(float4*)&out[r1i * DD + c0] = make_float4(s*a1x, s*a1y, s*a1z, s*a1w);
    }
}

// ---------------- pull aggregation (float4 gather, fused bias+relu) ---------
// h' rows are pre-scaled by dinv[src]; out[d] = relu(dinv[d]*(sum + self) + b).
// 384 threads = 16 nodes x 24 float4-lanes. 16B per outstanding load.

__global__ __launch_bounds__(384) void k_pull(const float4* __restrict__ h4,
                                              const int* __restrict__ rp,
                                              const int* __restrict__ col,
                                              const float* __restrict__ dinv,
                                              const float4* __restrict__ b4,
                                              float4* __restrict__ out4) {
    int c  = threadIdx.x % 24;   // float4 column
    int ny = threadIdx.x / 24;   // 0..15
    int d = blockIdx.x * 16 + ny;
    if (d >= NN) return;
    int j0 = rp[d], j1 = rp[d + 1];
    float4 a0 = {0,0,0,0}, a1 = {0,0,0,0}, a2 = {0,0,0,0}, a3 = {0,0,0,0};
    int j = j0;
    for (; j + 3 < j1; j += 4) {
        int s0 = col[j], s1 = col[j+1], s2 = col[j+2], s3 = col[j+3];
        float4 v0 = h4[s0 * 24 + c];
        float4 v1 = h4[s1 * 24 + c];
        float4 v2 = h4[s2 * 24 + c];
        float4 v3 = h4[s3 * 24 + c];
        a0.x += v0.x; a0.y += v0.y; a0.z += v0.z; a0.w += v0.w;
        a1.x += v1.x; a1.y += v1.y; a1.z += v1.z; a1.w += v1.w;
        a2.x += v2.x; a2.y += v2.y; a2.z += v2.z; a2.w += v2.w;
        a3.x += v3.x; a3.y += v3.y; a3.z += v3.z; a3.w += v3.w;
    }
    for (; j < j1; ++j) {
        float4 v = h4[col[j] * 24 + c];
        a0.x += v.x; a0.y += v.y; a0.z += v.z; a0.w += v.w;
    }
    float4 self = h4[d * 24 + c];     // self-loop: + dinv[d]*h[d] after dd mul
    float dd = dinv[d];
    float4 bb = b4[c];
    float4 r;
    r.x = fmaxf(dd * ((a0.x + a1.x) + (a2.x + a3.x) + self.x) + bb.x, 0.f);
    r.y = fmaxf(dd * ((a0.y + a1.y) + (a2.y + a3.y) + self.y) + bb.y, 0.f);
    r.z = fmaxf(dd * ((a0.z + a1.z) + (a2.z + a3.z) + self.z) + bb.z, 0.f);
    r.w = fmaxf(dd * ((a0.w + a1.w) + (a2.w + a3.w) + self.w) + bb.w, 0.f);
    out4[d * 24 + c] = r;
}

// ----------------------------------------------------------------------------

extern "C" void kernel_launch(void* const* d_in, const int* in_sizes, int n_in,
                              void* d_out, int out_size, void* d_ws, size_t ws_size,
                              hipStream_t stream) {
    const float* x  = (const float*)d_in[0];
    const int*   ei = (const int*)d_in[1];
    const float* W1 = (const float*)d_in[2];
    const float* b1 = (const float*)d_in[3];
    const float* W2 = (const float*)d_in[4];
    const float* b2 = (const float*)d_in[5];
    float* out = (float*)d_out;

    // Workspace: cnt, part/cursor, rp, col, dinv, bsum, tmp  (~23.2 MB)
    char* p = (char*)d_ws;
    int*   cnt    = (int*)p;   p += ((size_t)NN * 4 + 255) & ~(size_t)255;
    int*   part   = (int*)p;   p += ((size_t)NN * 4 + 255) & ~(size_t)255;  // doubles as fill cursor
    int*   rp     = (int*)p;   p += ((size_t)(NN + 1) * 4 + 255) & ~(size_t)255;
    int*   col    = (int*)p;   p += ((size_t)EE * 4 + 255) & ~(size_t)255;
    float* dinv   = (float*)p; p += ((size_t)NN * 4 + 255) & ~(size_t)255;
    int*   bsum   = (int*)p;   p += ((size_t)NB * 4 + 255) & ~(size_t)255;
    float* tmp    = (float*)p;                    // N*D floats (19.2 MB)

    // ---- CSR build ----
    k_zero<<<(NN + 255) / 256, 256, 0, stream>>>(cnt);
    k_count<<<(EE + 255) / 256, 256, 0, stream>>>(ei, cnt);
    k_bscan<<<NB, 256, 0, stream>>>(cnt, part, bsum);
    k_scan2<<<1, 256, 0, stream>>>(bsum);
    k_final<<<(NN + 255) / 256, 256, 0, stream>>>(cnt, part, bsum, rp, dinv);
    k_fill<<<(EE + 255) / 256, 256, 0, stream>>>(ei, rp, part, col);

    // ---- layer 1: tmp = dinv .* (x@W1) ; d_out = relu(agg(tmp)) ----
    k_gemm<<<(NN + 31) / 32, 384, 0, stream>>>(x, W1, dinv, tmp);
    k_pull<<<(NN + 15) / 16, 384, 0, stream>>>((const float4*)tmp, rp, col, dinv,
                                               (const float4*)b1, (float4*)out);

    // ---- layer 2: tmp = dinv .* (d_out@W2) ; d_out = relu(agg(tmp)) ----
    k_gemm<<<(NN + 31) / 32, 384, 0, stream>>>(out, W2, dinv, tmp);
    k_pull<<<(NN + 15) / 16, 384, 0, stream>>>((const float4*)tmp, rp, col, dinv,
                                               (const float4*)b2, (float4*)out);
}